// Round 1
// baseline (498.141 us; speedup 1.0000x reference)
//
#include <hip/hip_runtime.h>

static constexpr int NN = 100000;
static constexpr int NE = 2400000;

__global__ void k_init_deg(int* __restrict__ deg) {
    int i = blockIdx.x * 256 + threadIdx.x;
    if (i < NN) deg[i] = 1;  // self-loop
}

__global__ void k_count(const int* __restrict__ dst, int* __restrict__ deg) {
    int i = blockIdx.x * 256 + threadIdx.x;
    if (i < NE) atomicAdd(deg + dst[i], 1);
}

__global__ void k_dis(const int* __restrict__ deg, float* __restrict__ dis) {
    int i = blockIdx.x * 256 + threadIdx.x;
    if (i < NN) dis[i] = rsqrtf((float)deg[i]);
}

// acc[i] = v[i]*dis[i]^2 (+ bias)   -- self-loop contribution as init (no memset needed)
__global__ void k_init_scalar(const float* __restrict__ v, const float* __restrict__ dis,
                              float* __restrict__ acc, const float* __restrict__ bias) {
    int i = blockIdx.x * 256 + threadIdx.x;
    if (i < NN) {
        float d = dis[i];
        acc[i] = v[i] * d * d + (bias ? bias[0] : 0.0f);
    }
}

// acc[dst] += v[src]*dis[src]*dis[dst]
__global__ void k_edge_scalar(const int* __restrict__ src, const int* __restrict__ dst,
                              const float* __restrict__ v, const float* __restrict__ dis,
                              float* __restrict__ acc) {
    int i = blockIdx.x * 256 + threadIdx.x;
    if (i < NE) {
        int s = src[i], d = dst[i];
        atomicAdd(acc + d, v[s] * dis[s] * dis[d]);
    }
}

// fused: h1 = relu(agg1*W1 + b1) [32]; h2pre = h1 @ W2 [16]; agg2 init = h2pre*dis^2
// one thread per (node, g) : tid = i*16 + g
__global__ void k_linear12(const float* __restrict__ agg1, const float* __restrict__ dis,
                           const float* __restrict__ W1, const float* __restrict__ b1,
                           const float* __restrict__ W2,
                           float* __restrict__ h2pre, float* __restrict__ agg2) {
    int t = blockIdx.x * 256 + threadIdx.x;
    if (t >= NN * 16) return;
    int i = t >> 4, g = t & 15;
    float a = agg1[i];
    float acc = 0.0f;
#pragma unroll
    for (int f = 0; f < 32; ++f) {
        float h = fmaxf(a * W1[f] + b1[f], 0.0f);
        acc += h * W2[f * 16 + g];
    }
    h2pre[t] = acc;
    float d = dis[i];
    agg2[t] = acc * d * d;
}

// agg2[dst*16+g] += h2pre[src*16+g] * dis[src]*dis[dst]   (thread per edge-feature)
__global__ void k_edge_vec16(const int* __restrict__ src, const int* __restrict__ dst,
                             const float* __restrict__ h2pre, const float* __restrict__ dis,
                             float* __restrict__ agg2) {
    int t = blockIdx.x * 256 + threadIdx.x;
    if (t >= NE * 16) return;
    int e = t >> 4, g = t & 15;
    int s = src[e], d = dst[e];
    float norm = dis[s] * dis[d];
    atomicAdd(agg2 + d * 16 + g, h2pre[s * 16 + g] * norm);
}

// h2 = relu(agg2 + b2); t = h2 . W3 ; out init = t*dis^2 + b3 ; store t
__global__ void k_layer3pre(const float* __restrict__ agg2, const float* __restrict__ b2,
                            const float* __restrict__ W3, const float* __restrict__ b3,
                            const float* __restrict__ dis,
                            float* __restrict__ tbuf, float* __restrict__ out) {
    int i = blockIdx.x * 256 + threadIdx.x;
    if (i >= NN) return;
    float acc = 0.0f;
#pragma unroll
    for (int g = 0; g < 16; ++g) {
        float h = fmaxf(agg2[i * 16 + g] + b2[g], 0.0f);
        acc += h * W3[g];
    }
    tbuf[i] = acc;
    float d = dis[i];
    out[i] = acc * d * d + b3[0];
}

extern "C" void kernel_launch(void* const* d_in, const int* in_sizes, int n_in,
                              void* d_out, int out_size, void* d_ws, size_t ws_size,
                              hipStream_t stream) {
    const float* x  = (const float*)d_in[0];
    const int*   ei = (const int*)d_in[1];   // (2, NE) flat: row0 = src, row1 = dst
    const int* src = ei;
    const int* dst = ei + NE;
    const float* W1 = (const float*)d_in[2];
    const float* b1 = (const float*)d_in[3];
    const float* W2 = (const float*)d_in[4];
    const float* b2 = (const float*)d_in[5];
    const float* W3 = (const float*)d_in[6];
    const float* b3 = (const float*)d_in[7];
    float* out = (float*)d_out;

    char* w = (char*)d_ws;
    int*   deg   = (int*)w;    w += (size_t)NN * 4;
    float* dis   = (float*)w;  w += (size_t)NN * 4;
    float* agg1  = (float*)w;  w += (size_t)NN * 4;
    float* tbuf  = (float*)w;  w += (size_t)NN * 4;
    float* h2pre = (float*)w;  w += (size_t)NN * 16 * 4;
    float* agg2  = (float*)w;  w += (size_t)NN * 16 * 4;

    auto cdiv = [](int a, int b) { return (a + b - 1) / b; };
    dim3 B(256);

    // degree + normalization
    k_init_deg  <<<cdiv(NN, 256),      B, 0, stream>>>(deg);
    k_count     <<<cdiv(NE, 256),      B, 0, stream>>>(dst, deg);
    k_dis       <<<cdiv(NN, 256),      B, 0, stream>>>(deg, dis);

    // layer 1: aggregate scalar x, then (fused) 1->32->16 dense into h2pre, init agg2
    k_init_scalar<<<cdiv(NN, 256),     B, 0, stream>>>(x, dis, agg1, nullptr);
    k_edge_scalar<<<cdiv(NE, 256),     B, 0, stream>>>(src, dst, x, dis, agg1);
    k_linear12  <<<cdiv(NN * 16, 256), B, 0, stream>>>(agg1, dis, W1, b1, W2, h2pre, agg2);

    // layer 2: aggregate 16-float h2pre
    k_edge_vec16<<<cdiv(NE * 16, 256), B, 0, stream>>>(src, dst, h2pre, dis, agg2);

    // layer 3: per-node relu+dot -> scalar t, init out, aggregate scalar t
    k_layer3pre <<<cdiv(NN, 256),      B, 0, stream>>>(agg2, b2, W3, b3, dis, tbuf, out);
    k_edge_scalar<<<cdiv(NE, 256),     B, 0, stream>>>(src, dst, tbuf, dis, out);
}

// Round 2
// 353.739 us; speedup vs baseline: 1.4082x; 1.4082x over previous
//
#include <hip/hip_runtime.h>

static constexpr int NN  = 100000;
static constexpr int NE  = 2400000;
static constexpr int BSH = 7;            // bucket shift
static constexpr int BSZ = 128;          // nodes per bucket
static constexpr int NB  = (NN + BSZ - 1) / BSZ;   // 782 buckets
static constexpr int NBP = 1024;         // padded bucket count (for scans)
static constexpr int NPB = 256;          // partition blocks
static constexpr int SEG = NE / NPB;     // 9375 edges per partition block
static_assert(NPB * SEG == NE, "exact segmentation");
static_assert(NB <= NBP, "bucket padding");

// ---- partition phase: deterministic counting sort of edges by dst bucket ----

__global__ __launch_bounds__(256) void khist(const int* __restrict__ dst,
                                             unsigned* __restrict__ H) {
    __shared__ unsigned h[NBP];
    int b = blockIdx.x;
    for (int t = threadIdx.x; t < NBP; t += 256) h[t] = 0;
    __syncthreads();
    int base = b * SEG;
    for (int j = threadIdx.x; j < SEG; j += 256)
        atomicAdd(&h[(unsigned)dst[base + j] >> BSH], 1u);
    __syncthreads();
    for (int t = threadIdx.x; t < NBP; t += 256) H[b * NBP + t] = h[t];
}

// per-bucket exclusive scan over the 256 partition blocks; one block per bucket
__global__ __launch_bounds__(256) void kcolscan(const unsigned* __restrict__ H,
                                                unsigned* __restrict__ P,
                                                unsigned* __restrict__ Hsum) {
    __shared__ unsigned a[256], b2[256];
    int k = blockIdx.x, t = threadIdx.x;
    unsigned v = H[(size_t)t * NBP + k];
    a[t] = v;
    __syncthreads();
    unsigned* cur = a; unsigned* nxt = b2;
    for (int off = 1; off < 256; off <<= 1) {
        unsigned x = cur[t];
        if (t >= off) x += cur[t - off];
        nxt[t] = x;
        __syncthreads();
        unsigned* tmp = cur; cur = nxt; nxt = tmp;
    }
    unsigned incl = cur[t];
    P[(size_t)t * NBP + k] = incl - v;     // exclusive prefix over blocks
    if (t == 255) Hsum[k] = incl;          // bucket total
}

// exclusive scan of the 1024 bucket totals; single block
__global__ __launch_bounds__(1024) void kbscan(const unsigned* __restrict__ Hsum,
                                               unsigned* __restrict__ base) {
    __shared__ unsigned a[1024], b2[1024];
    int t = threadIdx.x;
    unsigned v = Hsum[t];
    a[t] = v;
    __syncthreads();
    unsigned* cur = a; unsigned* nxt = b2;
    for (int off = 1; off < 1024; off <<= 1) {
        unsigned x = cur[t];
        if (t >= off) x += cur[t - off];
        nxt[t] = x;
        __syncthreads();
        unsigned* tmp = cur; cur = nxt; nxt = tmp;
    }
    base[t] = cur[t] - v;                  // exclusive
}

__global__ __launch_bounds__(256) void kscatter(const int* __restrict__ src,
                                                const int* __restrict__ dst,
                                                const unsigned* __restrict__ P,
                                                const unsigned* __restrict__ base,
                                                unsigned* __restrict__ csr) {
    __shared__ unsigned cur[NBP];
    int b = blockIdx.x;
    for (int t = threadIdx.x; t < NBP; t += 256)
        cur[t] = base[t] + P[(size_t)b * NBP + t];
    __syncthreads();
    int off = b * SEG;
    for (int j = threadIdx.x; j < SEG; j += 256) {
        int d = dst[off + j], s = src[off + j];
        unsigned pos = atomicAdd(&cur[(unsigned)d >> BSH], 1u);
        csr[pos] = ((unsigned)s << BSH) | (unsigned)(d & (BSZ - 1));
    }
}

// ---- per-bucket degree -> dis = rsqrt(deg_in + 1 self-loop) ----
__global__ __launch_bounds__(256) void kdis(const unsigned* __restrict__ csr,
                                            const unsigned* __restrict__ base,
                                            const unsigned* __restrict__ Hsum,
                                            float* __restrict__ dis) {
    __shared__ int cnt[BSZ];
    int k = blockIdx.x, t = threadIdx.x;
    if (t < BSZ) cnt[t] = 0;
    __syncthreads();
    unsigned s0 = base[k], n = Hsum[k];
    for (unsigned j = t; j < n; j += 256)
        atomicAdd(&cnt[csr[s0 + j] & (BSZ - 1)], 1);
    __syncthreads();
    int node = k * BSZ + t;
    if (t < BSZ && node < NN) dis[node] = rsqrtf((float)(cnt[t] + 1));
}

__global__ __launch_bounds__(256) void ky1(const float* __restrict__ x,
                                           const float* __restrict__ dis,
                                           float* __restrict__ y1) {
    int i = blockIdx.x * 256 + threadIdx.x;
    if (i < NN) y1[i] = dis[i] * x[i];
}

// scalar bucketed aggregate: out[node] = dis[node]*(sum_in y[src] + y[node]) (+bias)
__global__ __launch_bounds__(256) void kaggs(const unsigned* __restrict__ csr,
                                             const unsigned* __restrict__ base,
                                             const unsigned* __restrict__ Hsum,
                                             const float* __restrict__ y,
                                             const float* __restrict__ dis,
                                             float* __restrict__ out,
                                             const float* __restrict__ bias) {
    __shared__ float acc[BSZ];
    int k = blockIdx.x, t = threadIdx.x;
    if (t < BSZ) acc[t] = 0.f;
    __syncthreads();
    unsigned s0 = base[k], n = Hsum[k];
    for (unsigned j = t; j < n; j += 256) {
        unsigned c = csr[s0 + j];
        atomicAdd(&acc[c & (BSZ - 1)], y[c >> BSH]);
    }
    __syncthreads();
    int node = k * BSZ + t;
    if (t < BSZ && node < NN) {
        float d = dis[node];
        out[node] = d * (acc[t] + y[node]) + (bias ? bias[0] : 0.f);
    }
}

// h1 = relu(agg1*W1+b1)[32]; h2pre = h1@W2[16]; y2 = dis * h2pre
__global__ __launch_bounds__(256) void klin12(const float* __restrict__ agg1,
                                              const float* __restrict__ dis,
                                              const float* __restrict__ W1,
                                              const float* __restrict__ b1,
                                              const float* __restrict__ W2,
                                              float* __restrict__ y2) {
    int t = blockIdx.x * 256 + threadIdx.x;
    if (t >= NN * 16) return;
    int i = t >> 4, g = t & 15;
    float a = agg1[i];
    float acc = 0.f;
#pragma unroll
    for (int f = 0; f < 32; ++f) {
        float h = fmaxf(a * W1[f] + b1[f], 0.f);
        acc += h * W2[f * 16 + g];
    }
    y2[t] = dis[i] * acc;
}

// 16-wide bucketed aggregate fused with layer-3 linear:
// agg2 = dis*(sum_in y2 + y2[node]) + b2 ; h2 = relu(agg2) ; y3 = dis*(h2.W3)
__global__ __launch_bounds__(256) void kagg16(const unsigned* __restrict__ csr,
                                              const unsigned* __restrict__ base,
                                              const unsigned* __restrict__ Hsum,
                                              const float* __restrict__ y2,
                                              const float* __restrict__ dis,
                                              const float* __restrict__ b2,
                                              const float* __restrict__ W3,
                                              float* __restrict__ y3) {
    __shared__ float acc[BSZ * 17];        // stride 17: bank-conflict-free
    int k = blockIdx.x, t = threadIdx.x;
    for (int i = t; i < BSZ * 17; i += 256) acc[i] = 0.f;
    __syncthreads();
    unsigned s0 = base[k], n = Hsum[k];
    for (unsigned j = t; j < n; j += 256) {
        unsigned c = csr[s0 + j];
        unsigned s = c >> BSH, l = c & (BSZ - 1);
        const float4* yp = (const float4*)(y2 + (size_t)s * 16);
        float* ap = acc + l * 17;
#pragma unroll
        for (int q = 0; q < 4; ++q) {
            float4 v = yp[q];
            atomicAdd(ap + q * 4 + 0, v.x);
            atomicAdd(ap + q * 4 + 1, v.y);
            atomicAdd(ap + q * 4 + 2, v.z);
            atomicAdd(ap + q * 4 + 3, v.w);
        }
    }
    __syncthreads();
    int node = k * BSZ + t;
    if (t < BSZ && node < NN) {
        float d = dis[node];
        const float* yn = y2 + (size_t)node * 16;
        float s = 0.f;
#pragma unroll
        for (int g = 0; g < 16; ++g) {
            float a2 = d * (acc[t * 17 + g] + yn[g]) + b2[g];
            s += fmaxf(a2, 0.f) * W3[g];
        }
        y3[node] = d * s;
    }
}

extern "C" void kernel_launch(void* const* d_in, const int* in_sizes, int n_in,
                              void* d_out, int out_size, void* d_ws, size_t ws_size,
                              hipStream_t stream) {
    const float* x  = (const float*)d_in[0];
    const int*   ei = (const int*)d_in[1];
    const int* src = ei;
    const int* dst = ei + NE;
    const float* W1 = (const float*)d_in[2];
    const float* b1 = (const float*)d_in[3];
    const float* W2 = (const float*)d_in[4];
    const float* b2 = (const float*)d_in[5];
    const float* W3 = (const float*)d_in[6];
    const float* b3 = (const float*)d_in[7];
    float* out = (float*)d_out;

    auto align256 = [](size_t v) { return (v + 255) & ~(size_t)255; };
    char* w = (char*)d_ws;
    auto carve = [&](size_t bytes) { char* p = w; w += align256(bytes); return p; };

    unsigned* csr   = (unsigned*)carve((size_t)NE * 4);          // 9.6 MB
    unsigned* Hsum  = (unsigned*)carve((size_t)NBP * 4);
    unsigned* basep = (unsigned*)carve((size_t)NBP * 4);
    float*    dis   = (float*)   carve((size_t)NN * 4);
    float*    y1    = (float*)   carve((size_t)NN * 4);
    float*    agg1  = (float*)   carve((size_t)NN * 4);          // aliased as y3 later
    // union region: {H, P} (partition only) overlapped with y2 (post-partition)
    char* un = carve((size_t)NN * 16 * 4 > 2 * (size_t)NPB * NBP * 4
                         ? (size_t)NN * 16 * 4
                         : 2 * (size_t)NPB * NBP * 4);           // 6.4 MB
    unsigned* H  = (unsigned*)un;
    unsigned* P  = (unsigned*)(un + (size_t)NPB * NBP * 4);
    float*    y2 = (float*)un;
    float*    y3 = agg1;   // agg1 dead after klin12

    auto cdiv = [](int a, int b) { return (a + b - 1) / b; };
    dim3 B(256);

    // build bucketed edge list (no global atomics)
    khist   <<<NPB, B, 0, stream>>>(dst, H);
    kcolscan<<<NBP, B, 0, stream>>>(H, P, Hsum);
    kbscan  <<<1, dim3(1024), 0, stream>>>(Hsum, basep);
    kscatter<<<NPB, B, 0, stream>>>(src, dst, P, basep, csr);

    // normalization
    kdis    <<<NB, B, 0, stream>>>(csr, basep, Hsum, dis);
    ky1     <<<cdiv(NN, 256), B, 0, stream>>>(x, dis, y1);

    // layer 1 aggregate (scalar), then dense 1->32->16 producing y2 = dis*h2pre
    kaggs   <<<NB, B, 0, stream>>>(csr, basep, Hsum, y1, dis, agg1, nullptr);
    klin12  <<<cdiv(NN * 16, 256), B, 0, stream>>>(agg1, dis, W1, b1, W2, y2);

    // layer 2 aggregate (16-wide) fused with layer-3 linear -> y3 = dis*(h2.W3)
    kagg16  <<<NB, B, 0, stream>>>(csr, basep, Hsum, y2, dis, b2, W3, y3);

    // layer 3 aggregate (scalar) -> out
    kaggs   <<<NB, B, 0, stream>>>(csr, basep, Hsum, y3, dis, out, b3);
}

// Round 3
// 141.757 us; speedup vs baseline: 3.5140x; 2.4954x over previous
//
#include <hip/hip_runtime.h>

static constexpr int NN  = 100000;
static constexpr int NE  = 2400000;
static constexpr int BSH = 7;            // bucket shift
static constexpr int BSZ = 128;          // nodes per bucket
static constexpr int NB  = (NN + BSZ - 1) / BSZ;   // 782 buckets
static constexpr int NBP = 1024;         // padded bucket count (for scans)
static constexpr int NPB = 256;          // partition blocks
static constexpr int SEG = NE / NPB;     // 9375 edges per partition block
static_assert(NPB * SEG == NE, "exact segmentation");
static_assert(NB <= NBP, "bucket padding");

// ---- partition phase: counting sort of edges by dst bucket ----

__global__ __launch_bounds__(256) void khist(const int* __restrict__ dst,
                                             unsigned* __restrict__ H) {
    __shared__ unsigned h[NBP];
    int b = blockIdx.x;
    for (int t = threadIdx.x; t < NBP; t += 256) h[t] = 0;
    __syncthreads();
    int base = b * SEG;
    for (int j = threadIdx.x; j < SEG; j += 256)
        atomicAdd(&h[(unsigned)dst[base + j] >> BSH], 1u);
    __syncthreads();
    for (int t = threadIdx.x; t < NBP; t += 256) H[b * NBP + t] = h[t];
}

// per-bucket exclusive scan over the 256 partition blocks; one block per bucket
__global__ __launch_bounds__(256) void kcolscan(const unsigned* __restrict__ H,
                                                unsigned* __restrict__ P,
                                                unsigned* __restrict__ Hsum) {
    __shared__ unsigned a[256], b2[256];
    int k = blockIdx.x, t = threadIdx.x;
    unsigned v = H[(size_t)t * NBP + k];
    a[t] = v;
    __syncthreads();
    unsigned* cur = a; unsigned* nxt = b2;
    for (int off = 1; off < 256; off <<= 1) {
        unsigned x = cur[t];
        if (t >= off) x += cur[t - off];
        nxt[t] = x;
        __syncthreads();
        unsigned* tmp = cur; cur = nxt; nxt = tmp;
    }
    unsigned incl = cur[t];
    P[(size_t)t * NBP + k] = incl - v;     // exclusive prefix over blocks
    if (t == 255) Hsum[k] = incl;          // bucket total
}

// exclusive scan of the 1024 bucket totals; single block
__global__ __launch_bounds__(1024) void kbscan(const unsigned* __restrict__ Hsum,
                                               unsigned* __restrict__ base) {
    __shared__ unsigned a[1024], b2[1024];
    int t = threadIdx.x;
    unsigned v = Hsum[t];
    a[t] = v;
    __syncthreads();
    unsigned* cur = a; unsigned* nxt = b2;
    for (int off = 1; off < 1024; off <<= 1) {
        unsigned x = cur[t];
        if (t >= off) x += cur[t - off];
        nxt[t] = x;
        __syncthreads();
        unsigned* tmp = cur; cur = nxt; nxt = tmp;
    }
    base[t] = cur[t] - v;                  // exclusive
}

__global__ __launch_bounds__(256) void kscatter(const int* __restrict__ src,
                                                const int* __restrict__ dst,
                                                const unsigned* __restrict__ P,
                                                const unsigned* __restrict__ base,
                                                unsigned* __restrict__ csr) {
    __shared__ unsigned cur[NBP];
    int b = blockIdx.x;
    for (int t = threadIdx.x; t < NBP; t += 256)
        cur[t] = base[t] + P[(size_t)b * NBP + t];
    __syncthreads();
    int off = b * SEG;
    for (int j = threadIdx.x; j < SEG; j += 256) {
        int d = dst[off + j], s = src[off + j];
        unsigned pos = atomicAdd(&cur[(unsigned)d >> BSH], 1u);
        csr[pos] = ((unsigned)s << BSH) | (unsigned)(d & (BSZ - 1));
    }
}

// ---- second pass: node-sorted CSR within each bucket + rowptr + dis ----
__global__ __launch_bounds__(256) void kcsr(const unsigned* __restrict__ csr,
                                            const unsigned* __restrict__ basep,
                                            const unsigned* __restrict__ Hsum,
                                            unsigned* __restrict__ csr2,
                                            unsigned* __restrict__ rowptr,
                                            float* __restrict__ dis) {
    __shared__ int cnt[BSZ];
    __shared__ int sa[BSZ], sb[BSZ];
    __shared__ unsigned cur[BSZ];
    int k = blockIdx.x, t = threadIdx.x;
    if (t < BSZ) cnt[t] = 0;
    __syncthreads();
    unsigned s0 = basep[k], n = Hsum[k];
    for (unsigned j = t; j < n; j += 256)
        atomicAdd(&cnt[csr[s0 + j] & (BSZ - 1)], 1);
    __syncthreads();
    if (t < BSZ) sa[t] = cnt[t];
    __syncthreads();
    int* c = sa; int* x = sb;
    for (int o = 1; o < BSZ; o <<= 1) {
        if (t < BSZ) { int v = c[t]; if (t >= o) v += c[t - o]; x[t] = v; }
        __syncthreads();
        int* tmp = c; c = x; x = tmp;
    }
    int node = k * BSZ + t;
    if (t < BSZ) {
        int excl = c[t] - cnt[t];
        cur[t] = (unsigned)excl;
        if (node < NN) {
            rowptr[node] = s0 + excl;
            dis[node] = rsqrtf((float)(cnt[t] + 1));
        }
    }
    if (k == 0 && t == 0) rowptr[NN] = NE;
    __syncthreads();
    for (unsigned j = t; j < n; j += 256) {
        unsigned cc = csr[s0 + j];
        unsigned pos = atomicAdd(&cur[cc & (BSZ - 1)], 1u);
        csr2[s0 + pos] = cc >> BSH;   // src node id, grouped by dst node
    }
}

__global__ __launch_bounds__(256) void ky1(const float* __restrict__ x,
                                           const float* __restrict__ dis,
                                           float* __restrict__ y1) {
    int i = blockIdx.x * 256 + threadIdx.x;
    if (i < NN) y1[i] = dis[i] * x[i];
}

// scalar gather aggregate: 4 lanes per node
// out[node] = dis*(sum_in y[src] + y[node]) (+bias)
__global__ __launch_bounds__(256) void kaggsg(const unsigned* __restrict__ srcs,
                                              const unsigned* __restrict__ rowptr,
                                              const float* __restrict__ y,
                                              const float* __restrict__ dis,
                                              float* __restrict__ out,
                                              const float* __restrict__ bias) {
    int t = threadIdx.x;
    int node = blockIdx.x * 64 + (t >> 2);
    int g = t & 3;
    if (node >= NN) return;
    unsigned r0 = rowptr[node], r1 = rowptr[node + 1];
    float sum = 0.f;
    for (unsigned j = r0 + g; j < r1; j += 4) sum += y[srcs[j]];
    sum += __shfl_xor(sum, 1, 4);
    sum += __shfl_xor(sum, 2, 4);
    if (g == 0) {
        float d = dis[node];
        out[node] = d * (sum + y[node]) + (bias ? bias[0] : 0.f);
    }
}

// h1 = relu(agg1*W1+b1)[32]; h2pre = h1@W2[16]; y2 = dis * h2pre
__global__ __launch_bounds__(256) void klin12(const float* __restrict__ agg1,
                                              const float* __restrict__ dis,
                                              const float* __restrict__ W1,
                                              const float* __restrict__ b1,
                                              const float* __restrict__ W2,
                                              float* __restrict__ y2) {
    int t = blockIdx.x * 256 + threadIdx.x;
    if (t >= NN * 16) return;
    int i = t >> 4, g = t & 15;
    float a = agg1[i];
    float acc = 0.f;
#pragma unroll
    for (int f = 0; f < 32; ++f) {
        float h = fmaxf(a * W1[f] + b1[f], 0.f);
        acc += h * W2[f * 16 + g];
    }
    y2[t] = dis[i] * acc;
}

// 16-wide gather aggregate fused with layer-3 linear. 16 lanes per node, lane g
// owns feature g: per edge one coalesced 64B load, register accumulation.
// a2 = dis*(sum_in y2 + y2[node]) + b2 ; y3 = dis * (relu(a2) . W3)
__global__ __launch_bounds__(256) void kagg16g(const unsigned* __restrict__ srcs,
                                               const unsigned* __restrict__ rowptr,
                                               const float* __restrict__ y2,
                                               const float* __restrict__ dis,
                                               const float* __restrict__ b2,
                                               const float* __restrict__ W3,
                                               float* __restrict__ y3) {
    int t = threadIdx.x;
    int node = blockIdx.x * 16 + (t >> 4);
    int g = t & 15;
    unsigned r0 = rowptr[node], r1 = rowptr[node + 1];
    float sum = 0.f;
    unsigned j = r0;
    for (; j + 4 <= r1; j += 4) {
        unsigned s0 = srcs[j], s1 = srcs[j + 1], s2 = srcs[j + 2], s3 = srcs[j + 3];
        float v0 = y2[(size_t)s0 * 16 + g];
        float v1 = y2[(size_t)s1 * 16 + g];
        float v2 = y2[(size_t)s2 * 16 + g];
        float v3 = y2[(size_t)s3 * 16 + g];
        sum += (v0 + v1) + (v2 + v3);
    }
    for (; j < r1; ++j) sum += y2[(size_t)srcs[j] * 16 + g];
    float d = dis[node];
    float a2 = d * (sum + y2[(size_t)node * 16 + g]) + b2[g];
    float hg = fmaxf(a2, 0.f) * W3[g];
    hg += __shfl_xor(hg, 1, 16);
    hg += __shfl_xor(hg, 2, 16);
    hg += __shfl_xor(hg, 4, 16);
    hg += __shfl_xor(hg, 8, 16);
    if (g == 0) y3[node] = d * hg;
}

extern "C" void kernel_launch(void* const* d_in, const int* in_sizes, int n_in,
                              void* d_out, int out_size, void* d_ws, size_t ws_size,
                              hipStream_t stream) {
    const float* x  = (const float*)d_in[0];
    const int*   ei = (const int*)d_in[1];
    const int* src = ei;
    const int* dst = ei + NE;
    const float* W1 = (const float*)d_in[2];
    const float* b1 = (const float*)d_in[3];
    const float* W2 = (const float*)d_in[4];
    const float* b2 = (const float*)d_in[5];
    const float* W3 = (const float*)d_in[6];
    const float* b3 = (const float*)d_in[7];
    float* out = (float*)d_out;

    auto align256 = [](size_t v) { return (v + 255) & ~(size_t)255; };
    char* w = (char*)d_ws;
    auto carve = [&](size_t bytes) { char* p = w; w += align256(bytes); return p; };

    // region A: bucket-sorted csr (dead after kcsr) -> reused as y2
    char* regA = carve((size_t)NE * 4);                       // 9.6 MB
    unsigned* csr = (unsigned*)regA;
    float*    y2  = (float*)regA;
    // region B: node-sorted csr2; H,P live here only during partition
    char* regB = carve((size_t)NE * 4);                       // 9.6 MB
    unsigned* csr2 = (unsigned*)regB;
    unsigned* H    = (unsigned*)regB;
    unsigned* P    = (unsigned*)(regB + (size_t)NPB * NBP * 4);
    unsigned* Hsum   = (unsigned*)carve((size_t)NBP * 4);
    unsigned* basep  = (unsigned*)carve((size_t)NBP * 4);
    unsigned* rowptr = (unsigned*)carve((size_t)(NN + 1) * 4);
    float*    dis    = (float*)   carve((size_t)NN * 4);
    float*    y1     = (float*)   carve((size_t)NN * 4);
    float*    agg1   = (float*)   carve((size_t)NN * 4);
    float*    y3     = agg1;   // agg1 dead after klin12

    auto cdiv = [](int a, int b) { return (a + b - 1) / b; };
    dim3 B(256);

    // build bucket-sorted edge list, then node-sorted CSR (+rowptr, dis)
    khist   <<<NPB, B, 0, stream>>>(dst, H);
    kcolscan<<<NBP, B, 0, stream>>>(H, P, Hsum);
    kbscan  <<<1, dim3(1024), 0, stream>>>(Hsum, basep);
    kscatter<<<NPB, B, 0, stream>>>(src, dst, P, basep, csr);
    kcsr    <<<NB,  B, 0, stream>>>(csr, basep, Hsum, csr2, rowptr, dis);

    ky1     <<<cdiv(NN, 256), B, 0, stream>>>(x, dis, y1);

    // layer 1 aggregate (scalar gather), then dense 1->32->16 -> y2 = dis*h2pre
    kaggsg  <<<cdiv(NN, 64), B, 0, stream>>>(csr2, rowptr, y1, dis, agg1, nullptr);
    klin12  <<<cdiv(NN * 16, 256), B, 0, stream>>>(agg1, dis, W1, b1, W2, y2);

    // layer 2 aggregate (16-wide gather) fused with layer-3 linear -> y3
    kagg16g <<<NN / 16, B, 0, stream>>>(csr2, rowptr, y2, dis, b2, W3, y3);

    // layer 3 aggregate (scalar gather) -> out
    kaggsg  <<<cdiv(NN, 64), B, 0, stream>>>(csr2, rowptr, y3, dis, out, b3);
}